// Round 1
// baseline (7197.012 us; speedup 1.0000x reference)
//
#include <hip/hip_runtime.h>
#include <math.h>

#define NB 64      // batch
#define TTX 256    // text timesteps
#define TTP 16     // topic timesteps
#define EE 300     // embedding dim
#define HH 512     // hidden

// ---------------------------------------------------------------------------
// init: zero the barrier flags (must run each call so graph replays are
// deterministic; flags are monotonically increasing within one launch)
// ---------------------------------------------------------------------------
__global__ void sd_init_flags(unsigned* __restrict__ flags, int n) {
  int i = blockIdx.x * blockDim.x + threadIdx.x;
  if (i < n) flags[i] = 0u;
}

// ---------------------------------------------------------------------------
// xproj: out[t*64+b][c] = sum_k emb[idx[b][t]][k] * W[k][c'] + bias[c']
//   c in [0,1024): c<512 -> Wz x-part, else Wo x-part. Rows of a block share t.
//   Tiled fp32 GEMM: BM=64 (all b at fixed t), BN=64, BK=12 (300 = 25*12).
// ---------------------------------------------------------------------------
__global__ __launch_bounds__(256) void sd_xproj(
    const int* __restrict__ idx, int T,
    const float* __restrict__ emb,
    const float* __restrict__ Wz, const float* __restrict__ Wo,
    const float* __restrict__ bz, const float* __restrict__ bo,
    float* __restrict__ xp)
{
  __shared__ int tok[64];
  __shared__ alignas(16) float As[12][64];
  __shared__ alignas(16) float Bs[12][64];

  const int tid = threadIdx.x;
  const int t   = blockIdx.x;        // rows r = t*64 + b, b = 0..63
  const int c0  = blockIdx.y * 64;   // col tile start in [0,1024)

  if (tid < 64) tok[tid] = idx[tid * T + t];

  const float* Wsel = (c0 < 512) ? Wz : Wo;
  const float* bsel = (c0 < 512) ? bz : bo;
  const int cc0 = (c0 < 512) ? c0 : (c0 - 512);

  const int tx = tid & 15;   // col group (4 cols)
  const int ty = tid >> 4;   // row group (4 rows)

  float acc[4][4];
#pragma unroll
  for (int i = 0; i < 4; ++i)
#pragma unroll
    for (int j = 0; j < 4; ++j) acc[i][j] = 0.f;

  __syncthreads();  // tok ready

  const int r   = tid & 63;
  const int k0l = tid >> 6;  // 0..3

  for (int kk = 0; kk < EE; kk += 12) {
    // global loads into regs first
    const size_t erow = (size_t)tok[r] * EE + kk + k0l;
    float a0 = emb[erow + 0];
    float a1 = emb[erow + 4];
    float a2 = emb[erow + 8];
    const int j = tid & 63;
    float b0v = Wsel[(size_t)(kk + k0l + 0) * HH + cc0 + j];
    float b1v = Wsel[(size_t)(kk + k0l + 4) * HH + cc0 + j];
    float b2v = Wsel[(size_t)(kk + k0l + 8) * HH + cc0 + j];
    __syncthreads();  // prior compute done before LDS overwrite
    As[k0l + 0][r] = a0;  As[k0l + 4][r] = a1;  As[k0l + 8][r] = a2;
    Bs[k0l + 0][j] = b0v; Bs[k0l + 4][j] = b1v; Bs[k0l + 8][j] = b2v;
    __syncthreads();
#pragma unroll
    for (int k = 0; k < 12; ++k) {
      float4 av = *(const float4*)&As[k][ty * 4];
      float4 bv = *(const float4*)&Bs[k][tx * 4];
      acc[0][0] += av.x * bv.x; acc[0][1] += av.x * bv.y; acc[0][2] += av.x * bv.z; acc[0][3] += av.x * bv.w;
      acc[1][0] += av.y * bv.x; acc[1][1] += av.y * bv.y; acc[1][2] += av.y * bv.z; acc[1][3] += av.y * bv.w;
      acc[2][0] += av.z * bv.x; acc[2][1] += av.z * bv.y; acc[2][2] += av.z * bv.z; acc[2][3] += av.z * bv.w;
      acc[3][0] += av.w * bv.x; acc[3][1] += av.w * bv.y; acc[3][2] += av.w * bv.z; acc[3][3] += av.w * bv.w;
    }
  }

  const float4 bias4 = *(const float4*)&bsel[cc0 + tx * 4];
#pragma unroll
  for (int i = 0; i < 4; ++i) {
    const size_t row = (size_t)t * 64 + (ty * 4 + i);
    float4 o;
    o.x = acc[i][0] + bias4.x;
    o.y = acc[i][1] + bias4.y;
    o.z = acc[i][2] + bias4.z;
    o.w = acc[i][3] + bias4.w;
    *(float4*)&xp[row * 1024 + c0 + tx * 4] = o;
  }
}

// ---------------------------------------------------------------------------
// Persistent recurrence kernel.
//   256 blocks = 16 batch-groups (4 rows each) x 16 dim-slices (32 dims each).
//   W h-part columns live in registers: wave kq holds k in [kq*128, kq*128+128),
//   lane = gate(2) x dim(32). Group-local barrier each step (16 blocks).
//   96KB LDS forces 1 block/CU -> all 256 blocks co-resident (spin-safe).
// ---------------------------------------------------------------------------
__global__ __launch_bounds__(256) void sd_recur(
    const float* __restrict__ tWz, const float* __restrict__ tWo,
    const float* __restrict__ pWz, const float* __restrict__ pWo,
    const float* __restrict__ xp_text, const float* __restrict__ xp_topic,
    float* __restrict__ text_out, float* __restrict__ hbuf,
    float* __restrict__ topic_h, unsigned* __restrict__ flags)
{
  __shared__ alignas(16) float smem[24576];  // 96KB: pad to force 1 block/CU
  float* h_s = smem;          // [4][512] staged h rows
  float* red = smem + 2048;   // [4 kq][2 gate][4 bi][32 d] partials

  const int tid = threadIdx.x;
  const int bid = blockIdx.x;
  const int x = bid & 7;           // XCD (heuristic placement)
  const int q = bid >> 3;          // 0..31
  const int g = x + 8 * (q >> 4);  // batch group 0..15
  const int slice = q & 15;        // dim slice 0..15
  const int b0 = g * 4;
  const int c_base = slice * 32;

  const int kq = tid >> 6;         // wave id = k-quarter
  const int lane = tid & 63;
  const int gt = lane >> 5;        // 0 = z gate, 1 = o gate
  const int d = lane & 31;
  const int c = c_base + d;

  const int bi_w = tid >> 5;       // writer mapping (tid<128): batch row 0..3
  const int dw = tid & 31;

  unsigned* gflags = flags + (size_t)g * 256;  // 16 slots, 64B apart
  unsigned barseq = 0;

  for (int ph = 0; ph < 2; ++ph) {
    const float* Wg = gt ? (ph ? pWo : tWo) : (ph ? pWz : tWz);
    const float* xp = ph ? xp_topic : xp_text;
    const int T = ph ? TTP : TTX;

    // load this lane's W h-part column slice into registers
    float wreg[128];
#pragma unroll
    for (int kk = 0; kk < 128; ++kk)
      wreg[kk] = Wg[(size_t)(EE + kq * 128 + kk) * HH + c];

    for (int t = 0; t < T; ++t) {
      // writers prefetch xp early (hidden under FMA phase)
      float xpz = 0.f, xpo = 0.f;
      if (tid < 128) {
        const float* xpr = xp + ((size_t)t * 64 + (b0 + bi_w)) * 1024 + c_base + dw;
        xpz = xpr[0];
        xpo = xpr[512];
      }

      float zp = 0.f, op = 0.f;
      if (t > 0) {
        // stage h rows b0..b0+3 (8KB) into LDS
        const float4* hsrc = (const float4*)(hbuf + (size_t)(t & 1) * NB * HH + (size_t)b0 * HH);
        float4* hdst = (float4*)h_s;
        for (int i = tid; i < 512; i += 256) hdst[i] = hsrc[i];
        __syncthreads();

        float acc0 = 0.f, acc1 = 0.f, acc2 = 0.f, acc3 = 0.f;
        const float* hq = h_s + kq * 128;
#pragma unroll
        for (int k4 = 0; k4 < 32; ++k4) {
          const float w0 = wreg[4 * k4 + 0], w1 = wreg[4 * k4 + 1];
          const float w2 = wreg[4 * k4 + 2], w3 = wreg[4 * k4 + 3];
          float4 h0v = *(const float4*)(hq + 0 * HH + 4 * k4);
          float4 h1v = *(const float4*)(hq + 1 * HH + 4 * k4);
          float4 h2v = *(const float4*)(hq + 2 * HH + 4 * k4);
          float4 h3v = *(const float4*)(hq + 3 * HH + 4 * k4);
          acc0 += h0v.x * w0 + h0v.y * w1 + h0v.z * w2 + h0v.w * w3;
          acc1 += h1v.x * w0 + h1v.y * w1 + h1v.z * w2 + h1v.w * w3;
          acc2 += h2v.x * w0 + h2v.y * w1 + h2v.z * w2 + h2v.w * w3;
          acc3 += h3v.x * w0 + h3v.y * w1 + h3v.z * w2 + h3v.w * w3;
        }
        // write partials: red[kq][gt][bi][d]
        float* rp = red + ((kq * 2 + gt) * 4) * 32 + d;
        rp[0 * 32] = acc0; rp[1 * 32] = acc1; rp[2 * 32] = acc2; rp[3 * 32] = acc3;
        __syncthreads();
        if (tid < 128) {
#pragma unroll
          for (int k2 = 0; k2 < 4; ++k2) {
            zp += red[((k2 * 2 + 0) * 4 + bi_w) * 32 + dw];
            op += red[((k2 * 2 + 1) * 4 + bi_w) * 32 + dw];
          }
        }
      }

      if (tid < 128) {
        const float z   = 1.f / (1.f + expf(-(zp + xpz)));
        const float htl = tanhf(op + xpo);
        const float hprev = (t > 0) ? h_s[bi_w * HH + c_base + dw] : 0.f;
        const float hn = (1.f - z) * hprev + z * htl;
        hbuf[(size_t)((t + 1) & 1) * NB * HH + (size_t)(b0 + bi_w) * HH + c_base + dw] = hn;
        if (ph == 0)
          text_out[((size_t)(b0 + bi_w) * TTX + t) * HH + c_base + dw] = hn;
        else if (t == T - 1)
          topic_h[(size_t)(b0 + bi_w) * HH + c_base + dw] = hn;
      }

      // group-local barrier (16 blocks sharing this batch group)
      __threadfence();
      __syncthreads();
      ++barseq;
      if (tid == 0)
        __hip_atomic_store(&gflags[slice * 16], barseq, __ATOMIC_RELEASE, __HIP_MEMORY_SCOPE_AGENT);
      if (tid < 16) {
        while (__hip_atomic_load(&gflags[tid * 16], __ATOMIC_ACQUIRE, __HIP_MEMORY_SCOPE_AGENT) < barseq)
          __builtin_amdgcn_s_sleep(1);
      }
      __syncthreads();
    }
  }
}

// ---------------------------------------------------------------------------
// attention: scores -> softmax weights (output) -> context
// ---------------------------------------------------------------------------
__global__ __launch_bounds__(256) void sd_att(
    const float* __restrict__ text_out, const float* __restrict__ topic_h,
    const float* __restrict__ att_W, const float* __restrict__ att_b,
    float* __restrict__ context, float* __restrict__ weights_out)
{
  __shared__ alignas(16) float aw[1024];
  __shared__ float sred[256];
  __shared__ float wsh[256];
  const int b = blockIdx.x, tid = threadIdx.x;

  for (int i = tid; i < 1024; i += 256) aw[i] = att_W[i];
  __syncthreads();

  float part = 0.f;
  for (int i = tid; i < 512; i += 256) part += topic_h[(size_t)b * HH + i] * aw[512 + i];
  sred[tid] = part;
  __syncthreads();
  for (int s = 128; s > 0; s >>= 1) { if (tid < s) sred[tid] += sred[tid + s]; __syncthreads(); }
  const float cb = sred[0] + att_b[0];
  __syncthreads();

  const float* row = text_out + ((size_t)b * TTX + tid) * HH;
  float sc = cb;
  for (int d4 = 0; d4 < 128; ++d4) {
    float4 v = ((const float4*)row)[d4];
    float4 w4 = ((const float4*)aw)[d4];
    sc += v.x * w4.x + v.y * w4.y + v.z * w4.z + v.w * w4.w;
  }
  sred[tid] = sc; __syncthreads();
  for (int s = 128; s > 0; s >>= 1) { if (tid < s) sred[tid] = fmaxf(sred[tid], sred[tid + s]); __syncthreads(); }
  const float m = sred[0];
  __syncthreads();
  const float e = expf(sc - m);
  sred[tid] = e; __syncthreads();
  for (int s = 128; s > 0; s >>= 1) { if (tid < s) sred[tid] += sred[tid + s]; __syncthreads(); }
  const float wv = e / sred[0];
  wsh[tid] = wv;
  weights_out[(size_t)b * TTX + tid] = wv;
  __syncthreads();

  for (int rep = 0; rep < 2; ++rep) {
    const int dcol = rep * 256 + tid;
    float accc = 0.f;
    const float* base = text_out + (size_t)b * TTX * HH + dcol;
    for (int t2 = 0; t2 < TTX; ++t2) accc += wsh[t2] * base[(size_t)t2 * HH];
    context[(size_t)b * HH + dcol] = accc;
  }
}

// ---------------------------------------------------------------------------
// FC head: feat=[context, topic_h] -> relu(fc1) -> fc2 logits
// ---------------------------------------------------------------------------
__global__ __launch_bounds__(256) void sd_fc(
    const float* __restrict__ context, const float* __restrict__ topic_h,
    const float* __restrict__ fc1_W, const float* __restrict__ fc1_b,
    const float* __restrict__ fc2_W, const float* __restrict__ fc2_b,
    float* __restrict__ logits)
{
  __shared__ alignas(16) float feat[1024];
  __shared__ float hid[512];
  const int b = blockIdx.x, tid = threadIdx.x;

  for (int i = tid; i < 512; i += 256) {
    feat[i]       = context[(size_t)b * HH + i];
    feat[512 + i] = topic_h[(size_t)b * HH + i];
  }
  __syncthreads();

  for (int rep = 0; rep < 2; ++rep) {
    const int dcol = rep * 256 + tid;
    float a = fc1_b[dcol];
#pragma unroll 4
    for (int j = 0; j < 1024; ++j) a += feat[j] * fc1_W[(size_t)j * HH + dcol];
    hid[dcol] = fmaxf(a, 0.f);
  }
  __syncthreads();

  float p0 = 0.f, p1 = 0.f, p2 = 0.f;
  for (int dv = tid; dv < 512; dv += 256) {
    const float hv = hid[dv];
    p0 += hv * fc2_W[dv * 3 + 0];
    p1 += hv * fc2_W[dv * 3 + 1];
    p2 += hv * fc2_W[dv * 3 + 2];
  }
  feat[tid] = p0; feat[256 + tid] = p1; feat[512 + tid] = p2;
  __syncthreads();
  for (int s = 128; s > 0; s >>= 1) {
    if (tid < s) {
      feat[tid] += feat[tid + s];
      feat[256 + tid] += feat[256 + tid + s];
      feat[512 + tid] += feat[512 + tid + s];
    }
    __syncthreads();
  }
  if (tid < 3) logits[b * 3 + tid] = feat[tid * 256] + fc2_b[tid];
}

// ---------------------------------------------------------------------------
extern "C" void kernel_launch(void* const* d_in, const int* in_sizes, int n_in,
                              void* d_out, int out_size, void* d_ws, size_t ws_size,
                              hipStream_t stream) {
  const int*   text  = (const int*)d_in[0];
  const int*   topic = (const int*)d_in[1];
  const float* emb   = (const float*)d_in[2];
  const float* tWz   = (const float*)d_in[3];
  const float* tbz   = (const float*)d_in[4];
  const float* tWo   = (const float*)d_in[5];
  const float* tbo   = (const float*)d_in[6];
  const float* pWz   = (const float*)d_in[7];
  const float* pbz   = (const float*)d_in[8];
  const float* pWo   = (const float*)d_in[9];
  const float* pbo   = (const float*)d_in[10];
  const float* attW  = (const float*)d_in[11];
  const float* attb  = (const float*)d_in[12];
  const float* fc1W  = (const float*)d_in[13];
  const float* fc1b  = (const float*)d_in[14];
  const float* fc2W  = (const float*)d_in[15];
  const float* fc2b  = (const float*)d_in[16];

  float* out = (float*)d_out;            // [0,192): logits, [192, 192+16384): weights
  float* ws  = (float*)d_ws;

  float* xp_text  = ws;                                    // 256*64*1024
  float* xp_topic = xp_text + (size_t)TTX * 64 * 1024;     // 16*64*1024
  float* text_o   = xp_topic + (size_t)TTP * 64 * 1024;    // 64*256*512
  float* hbuf     = text_o + (size_t)NB * TTX * HH;        // 2*64*512
  float* topic_hv = hbuf + (size_t)2 * NB * HH;            // 64*512
  float* ctx      = topic_hv + (size_t)NB * HH;            // 64*512
  unsigned* flags = (unsigned*)(ctx + (size_t)NB * HH);    // 16*16*16 u32

  sd_init_flags<<<dim3(16), dim3(256), 0, stream>>>(flags, 4096);
  sd_xproj<<<dim3(TTX, 16), dim3(256), 0, stream>>>(text, TTX, emb, tWz, tWo, tbz, tbo, xp_text);
  sd_xproj<<<dim3(TTP, 16), dim3(256), 0, stream>>>(topic, TTP, emb, pWz, pWo, pbz, pbo, xp_topic);
  sd_recur<<<dim3(256), dim3(256), 0, stream>>>(tWz, tWo, pWz, pWo, xp_text, xp_topic,
                                                text_o, hbuf, topic_hv, flags);
  sd_att<<<dim3(64), dim3(256), 0, stream>>>(text_o, topic_hv, attW, attb, ctx, out + 192);
  sd_fc<<<dim3(64), dim3(256), 0, stream>>>(ctx, topic_hv, fc1W, fc1b, fc2W, fc2b, out);
}

// Round 2
// 2001.356 us; speedup vs baseline: 3.5961x; 3.5961x over previous
//
#include <hip/hip_runtime.h>
#include <math.h>

#define NB 64      // batch
#define TTX 256    // text timesteps
#define TTP 16     // topic timesteps
#define EE 300     // embedding dim
#define HH 512     // hidden

// ---------------------------------------------------------------------------
// init: zero the barrier flags (must run each call so graph replays are
// deterministic; flags are monotonically increasing within one launch)
// ---------------------------------------------------------------------------
__global__ void sd_init_flags(unsigned* __restrict__ flags, int n) {
  int i = blockIdx.x * blockDim.x + threadIdx.x;
  if (i < n) flags[i] = 0u;
}

// ---------------------------------------------------------------------------
// xproj: out[t*64+b][c] = sum_k emb[idx[b][t]][k] * W[k][c'] + bias[c']
//   c in [0,1024): c<512 -> Wz x-part, else Wo x-part. Rows of a block share t.
//   Tiled fp32 GEMM: BM=64 (all b at fixed t), BN=64, BK=12 (300 = 25*12).
// ---------------------------------------------------------------------------
__global__ __launch_bounds__(256) void sd_xproj(
    const int* __restrict__ idx, int T,
    const float* __restrict__ emb,
    const float* __restrict__ Wz, const float* __restrict__ Wo,
    const float* __restrict__ bz, const float* __restrict__ bo,
    float* __restrict__ xp)
{
  __shared__ int tok[64];
  __shared__ alignas(16) float As[12][64];
  __shared__ alignas(16) float Bs[12][64];

  const int tid = threadIdx.x;
  const int t   = blockIdx.x;        // rows r = t*64 + b, b = 0..63
  const int c0  = blockIdx.y * 64;   // col tile start in [0,1024)

  if (tid < 64) tok[tid] = idx[tid * T + t];

  const float* Wsel = (c0 < 512) ? Wz : Wo;
  const float* bsel = (c0 < 512) ? bz : bo;
  const int cc0 = (c0 < 512) ? c0 : (c0 - 512);

  const int tx = tid & 15;   // col group (4 cols)
  const int ty = tid >> 4;   // row group (4 rows)

  float acc[4][4];
#pragma unroll
  for (int i = 0; i < 4; ++i)
#pragma unroll
    for (int j = 0; j < 4; ++j) acc[i][j] = 0.f;

  __syncthreads();  // tok ready

  const int r   = tid & 63;
  const int k0l = tid >> 6;  // 0..3

  for (int kk = 0; kk < EE; kk += 12) {
    // global loads into regs first
    const size_t erow = (size_t)tok[r] * EE + kk + k0l;
    float a0 = emb[erow + 0];
    float a1 = emb[erow + 4];
    float a2 = emb[erow + 8];
    const int j = tid & 63;
    float b0v = Wsel[(size_t)(kk + k0l + 0) * HH + cc0 + j];
    float b1v = Wsel[(size_t)(kk + k0l + 4) * HH + cc0 + j];
    float b2v = Wsel[(size_t)(kk + k0l + 8) * HH + cc0 + j];
    __syncthreads();  // prior compute done before LDS overwrite
    As[k0l + 0][r] = a0;  As[k0l + 4][r] = a1;  As[k0l + 8][r] = a2;
    Bs[k0l + 0][j] = b0v; Bs[k0l + 4][j] = b1v; Bs[k0l + 8][j] = b2v;
    __syncthreads();
#pragma unroll
    for (int k = 0; k < 12; ++k) {
      float4 av = *(const float4*)&As[k][ty * 4];
      float4 bv = *(const float4*)&Bs[k][tx * 4];
      acc[0][0] += av.x * bv.x; acc[0][1] += av.x * bv.y; acc[0][2] += av.x * bv.z; acc[0][3] += av.x * bv.w;
      acc[1][0] += av.y * bv.x; acc[1][1] += av.y * bv.y; acc[1][2] += av.y * bv.z; acc[1][3] += av.y * bv.w;
      acc[2][0] += av.z * bv.x; acc[2][1] += av.z * bv.y; acc[2][2] += av.z * bv.z; acc[2][3] += av.z * bv.w;
      acc[3][0] += av.w * bv.x; acc[3][1] += av.w * bv.y; acc[3][2] += av.w * bv.z; acc[3][3] += av.w * bv.w;
    }
  }

  const float4 bias4 = *(const float4*)&bsel[cc0 + tx * 4];
#pragma unroll
  for (int i = 0; i < 4; ++i) {
    const size_t row = (size_t)t * 64 + (ty * 4 + i);
    float4 o;
    o.x = acc[i][0] + bias4.x;
    o.y = acc[i][1] + bias4.y;
    o.z = acc[i][2] + bias4.z;
    o.w = acc[i][3] + bias4.w;
    *(float4*)&xp[row * 1024 + c0 + tx * 4] = o;
  }
}

// ---------------------------------------------------------------------------
// Persistent recurrence kernel.
//   256 blocks = 16 batch-groups (4 rows each) x 16 dim-slices (32 dims each).
//   W h-part columns live in registers: wave kq holds k in [kq*128, kq*128+128),
//   lane = gate(2) x dim(32). Group-local barrier each step (16 blocks).
//   96KB LDS forces 1 block/CU -> all 256 blocks co-resident (spin-safe).
//
//   Cross-block exchange uses RELAXED agent-scope atomics ONLY (sc1 loads /
//   stores -> device coherence point). No acquire/release fences: those lower
//   to buffer_inv/buffer_wbl2 L2 walks on gfx950 and were 95% of runtime.
//   Ordering: sc1 h-stores drained by s_waitcnt vmcnt(0) per wave +
//   __syncthreads (all waves) BEFORE the flag store; pollers issue their h
//   loads only after observing the flag, and those loads are themselves
//   device-coherent, so no cache maintenance is needed anywhere.
// ---------------------------------------------------------------------------
__global__ __launch_bounds__(256) void sd_recur(
    const float* __restrict__ tWz, const float* __restrict__ tWo,
    const float* __restrict__ pWz, const float* __restrict__ pWo,
    const float* __restrict__ xp_text, const float* __restrict__ xp_topic,
    float* __restrict__ text_out, float* __restrict__ hbuf,
    float* __restrict__ topic_h, unsigned* __restrict__ flags)
{
  __shared__ alignas(16) float smem[24576];  // 96KB: pad to force 1 block/CU
  float* h_s = smem;          // [4][512] staged h rows
  float* red = smem + 2048;   // [4 kq][2 gate][4 bi][32 d] partials

  const int tid = threadIdx.x;
  const int bid = blockIdx.x;
  const int x = bid & 7;           // XCD (heuristic placement)
  const int q = bid >> 3;          // 0..31
  const int g = x + 8 * (q >> 4);  // batch group 0..15
  const int slice = q & 15;        // dim slice 0..15
  const int b0 = g * 4;
  const int c_base = slice * 32;

  const int kq = tid >> 6;         // wave id = k-quarter
  const int lane = tid & 63;
  const int gt = lane >> 5;        // 0 = z gate, 1 = o gate
  const int d = lane & 31;
  const int c = c_base + d;

  const int bi_w = tid >> 5;       // writer mapping (tid<128): batch row 0..3
  const int dw = tid & 31;

  unsigned* gflags = flags + (size_t)g * 256;  // 16 slots, 64B apart
  unsigned barseq = 0;

  for (int ph = 0; ph < 2; ++ph) {
    const float* Wg = gt ? (ph ? pWo : tWo) : (ph ? pWz : tWz);
    const float* xp = ph ? xp_topic : xp_text;
    const int T = ph ? TTP : TTX;

    // load this lane's W h-part column slice into registers
    float wreg[128];
#pragma unroll
    for (int kk = 0; kk < 128; ++kk)
      wreg[kk] = Wg[(size_t)(EE + kq * 128 + kk) * HH + c];

    for (int t = 0; t < T; ++t) {
      // writers prefetch xp early (hidden under staging/FMA phase)
      float xpz = 0.f, xpo = 0.f;
      if (tid < 128) {
        const float* xpr = xp + ((size_t)t * 64 + (b0 + bi_w)) * 1024 + c_base + dw;
        xpz = xpr[0];
        xpo = xpr[512];
      }

      float zp = 0.f, op = 0.f;
      if (t > 0) {
        // stage h rows b0..b0+3 (8KB) into LDS via device-coherent loads
        const float* hsrc = hbuf + (size_t)(t & 1) * NB * HH + (size_t)b0 * HH;
#pragma unroll
        for (int j = 0; j < 8; ++j) {
          const int i = tid + j * 256;
          h_s[i] = __hip_atomic_load(&hsrc[i], __ATOMIC_RELAXED, __HIP_MEMORY_SCOPE_AGENT);
        }
        __syncthreads();

        float acc0 = 0.f, acc1 = 0.f, acc2 = 0.f, acc3 = 0.f;
        const float* hq = h_s + kq * 128;
#pragma unroll
        for (int k4 = 0; k4 < 32; ++k4) {
          const float w0 = wreg[4 * k4 + 0], w1 = wreg[4 * k4 + 1];
          const float w2 = wreg[4 * k4 + 2], w3 = wreg[4 * k4 + 3];
          float4 h0v = *(const float4*)(hq + 0 * HH + 4 * k4);
          float4 h1v = *(const float4*)(hq + 1 * HH + 4 * k4);
          float4 h2v = *(const float4*)(hq + 2 * HH + 4 * k4);
          float4 h3v = *(const float4*)(hq + 3 * HH + 4 * k4);
          acc0 += h0v.x * w0 + h0v.y * w1 + h0v.z * w2 + h0v.w * w3;
          acc1 += h1v.x * w0 + h1v.y * w1 + h1v.z * w2 + h1v.w * w3;
          acc2 += h2v.x * w0 + h2v.y * w1 + h2v.z * w2 + h2v.w * w3;
          acc3 += h3v.x * w0 + h3v.y * w1 + h3v.z * w2 + h3v.w * w3;
        }
        // write partials: red[kq][gt][bi][d]
        float* rp = red + ((kq * 2 + gt) * 4) * 32 + d;
        rp[0 * 32] = acc0; rp[1 * 32] = acc1; rp[2 * 32] = acc2; rp[3 * 32] = acc3;
        __syncthreads();
        if (tid < 128) {
#pragma unroll
          for (int k2 = 0; k2 < 4; ++k2) {
            zp += red[((k2 * 2 + 0) * 4 + bi_w) * 32 + dw];
            op += red[((k2 * 2 + 1) * 4 + bi_w) * 32 + dw];
          }
        }
      }

      if (tid < 128) {
        const float z   = 1.f / (1.f + expf(-(zp + xpz)));
        const float htl = tanhf(op + xpo);
        const float hprev = (t > 0) ? h_s[bi_w * HH + c_base + dw] : 0.f;
        const float hn = (1.f - z) * hprev + z * htl;
        // device-coherent store: lands at coherence point when vmcnt retires
        __hip_atomic_store(&hbuf[(size_t)((t + 1) & 1) * NB * HH + (size_t)(b0 + bi_w) * HH + c_base + dw],
                           hn, __ATOMIC_RELAXED, __HIP_MEMORY_SCOPE_AGENT);
        if (ph == 0)
          text_out[((size_t)(b0 + bi_w) * TTX + t) * HH + c_base + dw] = hn;
        else if (t == T - 1)
          topic_h[(size_t)(b0 + bi_w) * HH + c_base + dw] = hn;
      }

      // group-local barrier (16 blocks sharing this batch group).
      // Drain this wave's sc1 stores, then block-wide sync so ALL waves'
      // stores are at the coherence point before the flag is published.
      asm volatile("s_waitcnt vmcnt(0)" ::: "memory");
      __syncthreads();
      ++barseq;
      if (tid == 0)
        __hip_atomic_store(&gflags[slice * 16], barseq, __ATOMIC_RELAXED, __HIP_MEMORY_SCOPE_AGENT);
      if (tid < 16) {
        while (__hip_atomic_load(&gflags[tid * 16], __ATOMIC_RELAXED, __HIP_MEMORY_SCOPE_AGENT) < barseq)
          __builtin_amdgcn_s_sleep(2);
      }
      __syncthreads();
    }
  }
}

// ---------------------------------------------------------------------------
// attention: scores -> softmax weights (output) -> context
// ---------------------------------------------------------------------------
__global__ __launch_bounds__(256) void sd_att(
    const float* __restrict__ text_out, const float* __restrict__ topic_h,
    const float* __restrict__ att_W, const float* __restrict__ att_b,
    float* __restrict__ context, float* __restrict__ weights_out)
{
  __shared__ alignas(16) float aw[1024];
  __shared__ float sred[256];
  __shared__ float wsh[256];
  const int b = blockIdx.x, tid = threadIdx.x;

  for (int i = tid; i < 1024; i += 256) aw[i] = att_W[i];
  __syncthreads();

  float part = 0.f;
  for (int i = tid; i < 512; i += 256) part += topic_h[(size_t)b * HH + i] * aw[512 + i];
  sred[tid] = part;
  __syncthreads();
  for (int s = 128; s > 0; s >>= 1) { if (tid < s) sred[tid] += sred[tid + s]; __syncthreads(); }
  const float cb = sred[0] + att_b[0];
  __syncthreads();

  const float* row = text_out + ((size_t)b * TTX + tid) * HH;
  float sc = cb;
  for (int d4 = 0; d4 < 128; ++d4) {
    float4 v = ((const float4*)row)[d4];
    float4 w4 = ((const float4*)aw)[d4];
    sc += v.x * w4.x + v.y * w4.y + v.z * w4.z + v.w * w4.w;
  }
  sred[tid] = sc; __syncthreads();
  for (int s = 128; s > 0; s >>= 1) { if (tid < s) sred[tid] = fmaxf(sred[tid], sred[tid + s]); __syncthreads(); }
  const float m = sred[0];
  __syncthreads();
  const float e = expf(sc - m);
  sred[tid] = e; __syncthreads();
  for (int s = 128; s > 0; s >>= 1) { if (tid < s) sred[tid] += sred[tid + s]; __syncthreads(); }
  const float wv = e / sred[0];
  wsh[tid] = wv;
  weights_out[(size_t)b * TTX + tid] = wv;
  __syncthreads();

  for (int rep = 0; rep < 2; ++rep) {
    const int dcol = rep * 256 + tid;
    float accc = 0.f;
    const float* base = text_out + (size_t)b * TTX * HH + dcol;
    for (int t2 = 0; t2 < TTX; ++t2) accc += wsh[t2] * base[(size_t)t2 * HH];
    context[(size_t)b * HH + dcol] = accc;
  }
}

// ---------------------------------------------------------------------------
// FC head: feat=[context, topic_h] -> relu(fc1) -> fc2 logits
// ---------------------------------------------------------------------------
__global__ __launch_bounds__(256) void sd_fc(
    const float* __restrict__ context, const float* __restrict__ topic_h,
    const float* __restrict__ fc1_W, const float* __restrict__ fc1_b,
    const float* __restrict__ fc2_W, const float* __restrict__ fc2_b,
    float* __restrict__ logits)
{
  __shared__ alignas(16) float feat[1024];
  __shared__ float hid[512];
  const int b = blockIdx.x, tid = threadIdx.x;

  for (int i = tid; i < 512; i += 256) {
    feat[i]       = context[(size_t)b * HH + i];
    feat[512 + i] = topic_h[(size_t)b * HH + i];
  }
  __syncthreads();

  for (int rep = 0; rep < 2; ++rep) {
    const int dcol = rep * 256 + tid;
    float a = fc1_b[dcol];
#pragma unroll 4
    for (int j = 0; j < 1024; ++j) a += feat[j] * fc1_W[(size_t)j * HH + dcol];
    hid[dcol] = fmaxf(a, 0.f);
  }
  __syncthreads();

  float p0 = 0.f, p1 = 0.f, p2 = 0.f;
  for (int dv = tid; dv < 512; dv += 256) {
    const float hv = hid[dv];
    p0 += hv * fc2_W[dv * 3 + 0];
    p1 += hv * fc2_W[dv * 3 + 1];
    p2 += hv * fc2_W[dv * 3 + 2];
  }
  feat[tid] = p0; feat[256 + tid] = p1; feat[512 + tid] = p2;
  __syncthreads();
  for (int s = 128; s > 0; s >>= 1) {
    if (tid < s) {
      feat[tid] += feat[tid + s];
      feat[256 + tid] += feat[256 + tid + s];
      feat[512 + tid] += feat[512 + tid + s];
    }
    __syncthreads();
  }
  if (tid < 3) logits[b * 3 + tid] = feat[tid * 256] + fc2_b[tid];
}

// ---------------------------------------------------------------------------
extern "C" void kernel_launch(void* const* d_in, const int* in_sizes, int n_in,
                              void* d_out, int out_size, void* d_ws, size_t ws_size,
                              hipStream_t stream) {
  const int*   text  = (const int*)d_in[0];
  const int*   topic = (const int*)d_in[1];
  const float* emb   = (const float*)d_in[2];
  const float* tWz   = (const float*)d_in[3];
  const float* tbz   = (const float*)d_in[4];
  const float* tWo   = (const float*)d_in[5];
  const float* tbo   = (const float*)d_in[6];
  const float* pWz   = (const float*)d_in[7];
  const float* pbz   = (const float*)d_in[8];
  const float* pWo   = (const float*)d_in[9];
  const float* pbo   = (const float*)d_in[10];
  const float* attW  = (const float*)d_in[11];
  const float* attb  = (const float*)d_in[12];
  const float* fc1W  = (const float*)d_in[13];
  const float* fc1b  = (const float*)d_in[14];
  const float* fc2W  = (const float*)d_in[15];
  const float* fc2b  = (const float*)d_in[16];

  float* out = (float*)d_out;            // [0,192): logits, [192, 192+16384): weights
  float* ws  = (float*)d_ws;

  float* xp_text  = ws;                                    // 256*64*1024
  float* xp_topic = xp_text + (size_t)TTX * 64 * 1024;     // 16*64*1024
  float* text_o   = xp_topic + (size_t)TTP * 64 * 1024;    // 64*256*512
  float* hbuf     = text_o + (size_t)NB * TTX * HH;        // 2*64*512
  float* topic_hv = hbuf + (size_t)2 * NB * HH;            // 64*512
  float* ctx      = topic_hv + (size_t)NB * HH;            // 64*512
  unsigned* flags = (unsigned*)(ctx + (size_t)NB * HH);    // 16*16*16 u32

  sd_init_flags<<<dim3(16), dim3(256), 0, stream>>>(flags, 4096);
  sd_xproj<<<dim3(TTX, 16), dim3(256), 0, stream>>>(text, TTX, emb, tWz, tWo, tbz, tbo, xp_text);
  sd_xproj<<<dim3(TTP, 16), dim3(256), 0, stream>>>(topic, TTP, emb, pWz, pWo, pbz, pbo, xp_topic);
  sd_recur<<<dim3(256), dim3(256), 0, stream>>>(tWz, tWo, pWz, pWo, xp_text, xp_topic,
                                                text_o, hbuf, topic_hv, flags);
  sd_att<<<dim3(64), dim3(256), 0, stream>>>(text_o, topic_hv, attW, attb, ctx, out + 192);
  sd_fc<<<dim3(64), dim3(256), 0, stream>>>(ctx, topic_hv, fc1W, fc1b, fc2W, fc2b, out);
}

// Round 3
// 1263.884 us; speedup vs baseline: 5.6944x; 1.5835x over previous
//
#include <hip/hip_runtime.h>
#include <math.h>

#define NB 64      // batch
#define TTX 256    // text timesteps
#define TTP 16     // topic timesteps
#define EE 300     // embedding dim
#define HH 512     // hidden
#define SENT 0x7FC0DEADu   // NaN-payload sentinel; real h can never be NaN

// ---------------------------------------------------------------------------
// init: poison all 4 h-ring slots (must run each call: graph replays must be
// deterministic and the ring ends a call full of real values)
// ---------------------------------------------------------------------------
__global__ void sd_init_ring(unsigned* __restrict__ hring) {
  hring[blockIdx.x * blockDim.x + threadIdx.x] = SENT;  // grid == 4*NB*HH
}

// ---------------------------------------------------------------------------
// xproj: out[t*64+b][c] = sum_k emb[idx[b][t]][k] * W[k][c'] + bias[c']
// (unchanged from round 2)
// ---------------------------------------------------------------------------
__global__ __launch_bounds__(256) void sd_xproj(
    const int* __restrict__ idx, int T,
    const float* __restrict__ emb,
    const float* __restrict__ Wz, const float* __restrict__ Wo,
    const float* __restrict__ bz, const float* __restrict__ bo,
    float* __restrict__ xp)
{
  __shared__ int tok[64];
  __shared__ alignas(16) float As[12][64];
  __shared__ alignas(16) float Bs[12][64];

  const int tid = threadIdx.x;
  const int t   = blockIdx.x;
  const int c0  = blockIdx.y * 64;

  if (tid < 64) tok[tid] = idx[tid * T + t];

  const float* Wsel = (c0 < 512) ? Wz : Wo;
  const float* bsel = (c0 < 512) ? bz : bo;
  const int cc0 = (c0 < 512) ? c0 : (c0 - 512);

  const int tx = tid & 15;
  const int ty = tid >> 4;

  float acc[4][4];
#pragma unroll
  for (int i = 0; i < 4; ++i)
#pragma unroll
    for (int j = 0; j < 4; ++j) acc[i][j] = 0.f;

  __syncthreads();

  const int r   = tid & 63;
  const int k0l = tid >> 6;

  for (int kk = 0; kk < EE; kk += 12) {
    const size_t erow = (size_t)tok[r] * EE + kk + k0l;
    float a0 = emb[erow + 0];
    float a1 = emb[erow + 4];
    float a2 = emb[erow + 8];
    const int j = tid & 63;
    float b0v = Wsel[(size_t)(kk + k0l + 0) * HH + cc0 + j];
    float b1v = Wsel[(size_t)(kk + k0l + 4) * HH + cc0 + j];
    float b2v = Wsel[(size_t)(kk + k0l + 8) * HH + cc0 + j];
    __syncthreads();
    As[k0l + 0][r] = a0;  As[k0l + 4][r] = a1;  As[k0l + 8][r] = a2;
    Bs[k0l + 0][j] = b0v; Bs[k0l + 4][j] = b1v; Bs[k0l + 8][j] = b2v;
    __syncthreads();
#pragma unroll
    for (int k = 0; k < 12; ++k) {
      float4 av = *(const float4*)&As[k][ty * 4];
      float4 bv = *(const float4*)&Bs[k][tx * 4];
      acc[0][0] += av.x * bv.x; acc[0][1] += av.x * bv.y; acc[0][2] += av.x * bv.z; acc[0][3] += av.x * bv.w;
      acc[1][0] += av.y * bv.x; acc[1][1] += av.y * bv.y; acc[1][2] += av.y * bv.z; acc[1][3] += av.y * bv.w;
      acc[2][0] += av.z * bv.x; acc[2][1] += av.z * bv.y; acc[2][2] += av.z * bv.z; acc[2][3] += av.z * bv.w;
      acc[3][0] += av.w * bv.x; acc[3][1] += av.w * bv.y; acc[3][2] += av.w * bv.z; acc[3][3] += av.w * bv.w;
    }
  }

  const float4 bias4 = *(const float4*)&bsel[cc0 + tx * 4];
#pragma unroll
  for (int i = 0; i < 4; ++i) {
    const size_t row = (size_t)t * 64 + (ty * 4 + i);
    float4 o;
    o.x = acc[i][0] + bias4.x;
    o.y = acc[i][1] + bias4.y;
    o.z = acc[i][2] + bias4.z;
    o.w = acc[i][3] + bias4.w;
    *(float4*)&xp[row * 1024 + c0 + tx * 4] = o;
  }
}

// ---------------------------------------------------------------------------
// Persistent recurrence kernel, sentinel-ring edition.
//   256 blocks = 16 batch-groups x 16 dim-slices. W h-columns in registers.
//   Cross-block exchange: 4-deep ring hring[slot][b][k] of sc1 (agent,relaxed)
//   words. h(u) lives in slot u&3, written at step u-1, consumed at step u.
//   Readers poll the data words directly for != SENT (one MALL hop).
//   Slot recycling safety:
//     - poison own stripe of slot (u-1)&3 only AFTER block-wide poll of slot
//       u&3 succeeded (poll success => all producers stored h(u) => all blocks
//       finished reading slot (u-1)&3, since poll precedes store in each step)
//     - vmcnt(0) before the real h-store => poison is at the coherence point
//       before the next real value is visible; same-thread same-address
//       ordering does the rest. Readers therefore never see a stale real.
//   2 syncthreads/step; h_s and red double-buffered so there is no trailing
//   barrier (waves may skew by up to one phase).
// ---------------------------------------------------------------------------
__global__ __launch_bounds__(256) void sd_recur(
    const float* __restrict__ tWz, const float* __restrict__ tWo,
    const float* __restrict__ pWz, const float* __restrict__ pWo,
    const float* __restrict__ xp_text, const float* __restrict__ xp_topic,
    float* __restrict__ text_out, unsigned* __restrict__ hring,
    float* __restrict__ topic_h)
{
  __shared__ alignas(16) float h_s[2][4 * HH];   // staged h rows, double-buffered
  __shared__ alignas(16) float red[2][1024];     // k-quarter partials, double-buffered

  const int tid = threadIdx.x;
  const int bid = blockIdx.x;
  const int x = bid & 7;           // XCD (heuristic placement)
  const int q = bid >> 3;
  const int g = x + 8 * (q >> 4);  // batch group 0..15
  const int slice = q & 15;        // dim slice 0..15
  const int b0 = g * 4;
  const int c_base = slice * 32;

  const int kq = tid >> 6;         // wave id = k-quarter
  const int lane = tid & 63;
  const int gt = lane >> 5;        // 0 = z gate, 1 = o gate
  const int d = lane & 31;
  const int c = c_base + d;

  const int bi_w = tid >> 5;       // writer mapping (tid<128): batch row 0..3
  const int dw = tid & 31;

  // writer thread's private ring word offset (within a slot)
  const size_t wslot_off = (size_t)(b0 + bi_w) * HH + c_base + dw;

  int u = 0;  // global step counter across both phases

  for (int ph = 0; ph < 2; ++ph) {
    const float* Wg = gt ? (ph ? pWo : tWo) : (ph ? pWz : tWz);
    const float* xp = ph ? xp_topic : xp_text;
    const int T = ph ? TTP : TTX;

    // load this lane's W h-part column slice into registers
    float wreg[128];
#pragma unroll
    for (int kk = 0; kk < 128; ++kk)
      wreg[kk] = Wg[(size_t)(EE + kq * 128 + kk) * HH + c];

    for (int t = 0; t < T; ++t, ++u) {
      const int cur = u & 1;
      const bool do_poll = (u > 0);
      const bool use_h   = (t > 0);

      // xp prefetch early (latency hidden under poll + FMA)
      float xpz = 0.f, xpo = 0.f;
      if (tid < 128) {
        const float* xpr = xp + ((size_t)t * 64 + (b0 + bi_w)) * 1024 + c_base + dw;
        xpz = xpr[0];
        xpo = xpr[512];
      }

      if (do_poll) {
        // poll-stage 2048 words of slot u&3 (8 words/thread) into LDS
        const unsigned* src = hring + (size_t)(u & 3) * NB * HH + (size_t)b0 * HH;
        unsigned v0, v1, v2, v3, v4, v5, v6, v7;
        for (;;) {
          v0 = __hip_atomic_load(&src[tid + 0 * 256], __ATOMIC_RELAXED, __HIP_MEMORY_SCOPE_AGENT);
          v1 = __hip_atomic_load(&src[tid + 1 * 256], __ATOMIC_RELAXED, __HIP_MEMORY_SCOPE_AGENT);
          v2 = __hip_atomic_load(&src[tid + 2 * 256], __ATOMIC_RELAXED, __HIP_MEMORY_SCOPE_AGENT);
          v3 = __hip_atomic_load(&src[tid + 3 * 256], __ATOMIC_RELAXED, __HIP_MEMORY_SCOPE_AGENT);
          v4 = __hip_atomic_load(&src[tid + 4 * 256], __ATOMIC_RELAXED, __HIP_MEMORY_SCOPE_AGENT);
          v5 = __hip_atomic_load(&src[tid + 5 * 256], __ATOMIC_RELAXED, __HIP_MEMORY_SCOPE_AGENT);
          v6 = __hip_atomic_load(&src[tid + 6 * 256], __ATOMIC_RELAXED, __HIP_MEMORY_SCOPE_AGENT);
          v7 = __hip_atomic_load(&src[tid + 7 * 256], __ATOMIC_RELAXED, __HIP_MEMORY_SCOPE_AGENT);
          if (v0 != SENT && v1 != SENT && v2 != SENT && v3 != SENT &&
              v4 != SENT && v5 != SENT && v6 != SENT && v7 != SENT) break;
          __builtin_amdgcn_s_sleep(1);
        }
        h_s[cur][tid + 0 * 256] = __uint_as_float(v0);
        h_s[cur][tid + 1 * 256] = __uint_as_float(v1);
        h_s[cur][tid + 2 * 256] = __uint_as_float(v2);
        h_s[cur][tid + 3 * 256] = __uint_as_float(v3);
        h_s[cur][tid + 4 * 256] = __uint_as_float(v4);
        h_s[cur][tid + 5 * 256] = __uint_as_float(v5);
        h_s[cur][tid + 6 * 256] = __uint_as_float(v6);
        h_s[cur][tid + 7 * 256] = __uint_as_float(v7);
      }

      __syncthreads();  // whole block's poll complete + stage visible

      // Safe to recycle slot (u-1)&3 now (see header proof).
      if (do_poll && tid < 128)
        __hip_atomic_store(&hring[(size_t)((u - 1) & 3) * NB * HH + wslot_off],
                           SENT, __ATOMIC_RELAXED, __HIP_MEMORY_SCOPE_AGENT);

      if (use_h) {
        float acc0 = 0.f, acc1 = 0.f, acc2 = 0.f, acc3 = 0.f;
        const float* hq = &h_s[cur][kq * 128];
#pragma unroll
        for (int k4 = 0; k4 < 32; ++k4) {
          const float w0 = wreg[4 * k4 + 0], w1 = wreg[4 * k4 + 1];
          const float w2 = wreg[4 * k4 + 2], w3 = wreg[4 * k4 + 3];
          float4 h0v = *(const float4*)(hq + 0 * HH + 4 * k4);
          float4 h1v = *(const float4*)(hq + 1 * HH + 4 * k4);
          float4 h2v = *(const float4*)(hq + 2 * HH + 4 * k4);
          float4 h3v = *(const float4*)(hq + 3 * HH + 4 * k4);
          acc0 += h0v.x * w0 + h0v.y * w1 + h0v.z * w2 + h0v.w * w3;
          acc1 += h1v.x * w0 + h1v.y * w1 + h1v.z * w2 + h1v.w * w3;
          acc2 += h2v.x * w0 + h2v.y * w1 + h2v.z * w2 + h2v.w * w3;
          acc3 += h3v.x * w0 + h3v.y * w1 + h3v.z * w2 + h3v.w * w3;
        }
        float* rp = &red[cur][((kq * 2 + gt) * 4) * 32 + d];
        rp[0 * 32] = acc0; rp[1 * 32] = acc1; rp[2 * 32] = acc2; rp[3 * 32] = acc3;
      }

      __syncthreads();  // partials visible

      if (tid < 128) {
        float zp = 0.f, op = 0.f;
        if (use_h) {
#pragma unroll
          for (int k2 = 0; k2 < 4; ++k2) {
            zp += red[cur][((k2 * 2 + 0) * 4 + bi_w) * 32 + dw];
            op += red[cur][((k2 * 2 + 1) * 4 + bi_w) * 32 + dw];
          }
        }
        const float a = zp + xpz;
        const float z = 1.f / (1.f + __expf(-a));
        const float bv = op + xpo;
        const float ab = fabsf(bv);
        const float e2 = __expf(-2.f * ab);
        const float htl = __builtin_copysignf((1.f - e2) / (1.f + e2), bv);
        const float hprev = use_h ? h_s[cur][bi_w * HH + c_base + dw] : 0.f;
        const float hn = (1.f - z) * hprev + z * htl;

        // order: this step's poison must be at the coherence point before the
        // real store below becomes visible (stale-real proof in header)
        asm volatile("s_waitcnt vmcnt(0)" ::: "memory");
        __hip_atomic_store(&hring[(size_t)((u + 1) & 3) * NB * HH + wslot_off],
                           __float_as_uint(hn), __ATOMIC_RELAXED, __HIP_MEMORY_SCOPE_AGENT);
        if (ph == 0)
          text_out[((size_t)(b0 + bi_w) * TTX + t) * HH + c_base + dw] = hn;
        else if (t == T - 1)
          topic_h[(size_t)(b0 + bi_w) * HH + c_base + dw] = hn;
      }
      // no trailing barrier: h_s/red double-buffering tolerates one-phase skew
    }
  }
}

// ---------------------------------------------------------------------------
// attention: scores -> softmax weights (output) -> context  (unchanged)
// ---------------------------------------------------------------------------
__global__ __launch_bounds__(256) void sd_att(
    const float* __restrict__ text_out, const float* __restrict__ topic_h,
    const float* __restrict__ att_W, const float* __restrict__ att_b,
    float* __restrict__ context, float* __restrict__ weights_out)
{
  __shared__ alignas(16) float aw[1024];
  __shared__ float sred[256];
  __shared__ float wsh[256];
  const int b = blockIdx.x, tid = threadIdx.x;

  for (int i = tid; i < 1024; i += 256) aw[i] = att_W[i];
  __syncthreads();

  float part = 0.f;
  for (int i = tid; i < 512; i += 256) part += topic_h[(size_t)b * HH + i] * aw[512 + i];
  sred[tid] = part;
  __syncthreads();
  for (int s = 128; s > 0; s >>= 1) { if (tid < s) sred[tid] += sred[tid + s]; __syncthreads(); }
  const float cb = sred[0] + att_b[0];
  __syncthreads();

  const float* row = text_out + ((size_t)b * TTX + tid) * HH;
  float sc = cb;
  for (int d4 = 0; d4 < 128; ++d4) {
    float4 v = ((const float4*)row)[d4];
    float4 w4 = ((const float4*)aw)[d4];
    sc += v.x * w4.x + v.y * w4.y + v.z * w4.z + v.w * w4.w;
  }
  sred[tid] = sc; __syncthreads();
  for (int s = 128; s > 0; s >>= 1) { if (tid < s) sred[tid] = fmaxf(sred[tid], sred[tid + s]); __syncthreads(); }
  const float m = sred[0];
  __syncthreads();
  const float e = expf(sc - m);
  sred[tid] = e; __syncthreads();
  for (int s = 128; s > 0; s >>= 1) { if (tid < s) sred[tid] += sred[tid + s]; __syncthreads(); }
  const float wv = e / sred[0];
  wsh[tid] = wv;
  weights_out[(size_t)b * TTX + tid] = wv;
  __syncthreads();

  for (int rep = 0; rep < 2; ++rep) {
    const int dcol = rep * 256 + tid;
    float accc = 0.f;
    const float* base = text_out + (size_t)b * TTX * HH + dcol;
    for (int t2 = 0; t2 < TTX; ++t2) accc += wsh[t2] * base[(size_t)t2 * HH];
    context[(size_t)b * HH + dcol] = accc;
  }
}

// ---------------------------------------------------------------------------
// FC head: feat=[context, topic_h] -> relu(fc1) -> fc2 logits  (unchanged)
// ---------------------------------------------------------------------------
__global__ __launch_bounds__(256) void sd_fc(
    const float* __restrict__ context, const float* __restrict__ topic_h,
    const float* __restrict__ fc1_W, const float* __restrict__ fc1_b,
    const float* __restrict__ fc2_W, const float* __restrict__ fc2_b,
    float* __restrict__ logits)
{
  __shared__ alignas(16) float feat[1024];
  __shared__ float hid[512];
  const int b = blockIdx.x, tid = threadIdx.x;

  for (int i = tid; i < 512; i += 256) {
    feat[i]       = context[(size_t)b * HH + i];
    feat[512 + i] = topic_h[(size_t)b * HH + i];
  }
  __syncthreads();

  for (int rep = 0; rep < 2; ++rep) {
    const int dcol = rep * 256 + tid;
    float a = fc1_b[dcol];
#pragma unroll 4
    for (int j = 0; j < 1024; ++j) a += feat[j] * fc1_W[(size_t)j * HH + dcol];
    hid[dcol] = fmaxf(a, 0.f);
  }
  __syncthreads();

  float p0 = 0.f, p1 = 0.f, p2 = 0.f;
  for (int dv = tid; dv < 512; dv += 256) {
    const float hv = hid[dv];
    p0 += hv * fc2_W[dv * 3 + 0];
    p1 += hv * fc2_W[dv * 3 + 1];
    p2 += hv * fc2_W[dv * 3 + 2];
  }
  feat[tid] = p0; feat[256 + tid] = p1; feat[512 + tid] = p2;
  __syncthreads();
  for (int s = 128; s > 0; s >>= 1) {
    if (tid < s) {
      feat[tid] += feat[tid + s];
      feat[256 + tid] += feat[256 + tid + s];
      feat[512 + tid] += feat[512 + tid + s];
    }
    __syncthreads();
  }
  if (tid < 3) logits[b * 3 + tid] = feat[tid * 256] + fc2_b[tid];
}

// ---------------------------------------------------------------------------
extern "C" void kernel_launch(void* const* d_in, const int* in_sizes, int n_in,
                              void* d_out, int out_size, void* d_ws, size_t ws_size,
                              hipStream_t stream) {
  const int*   text  = (const int*)d_in[0];
  const int*   topic = (const int*)d_in[1];
  const float* emb   = (const float*)d_in[2];
  const float* tWz   = (const float*)d_in[3];
  const float* tbz   = (const float*)d_in[4];
  const float* tWo   = (const float*)d_in[5];
  const float* tbo   = (const float*)d_in[6];
  const float* pWz   = (const float*)d_in[7];
  const float* pbz   = (const float*)d_in[8];
  const float* pWo   = (const float*)d_in[9];
  const float* pbo   = (const float*)d_in[10];
  const float* attW  = (const float*)d_in[11];
  const float* attb  = (const float*)d_in[12];
  const float* fc1W  = (const float*)d_in[13];
  const float* fc1b  = (const float*)d_in[14];
  const float* fc2W  = (const float*)d_in[15];
  const float* fc2b  = (const float*)d_in[16];

  float* out = (float*)d_out;            // [0,192): logits, [192,+16384): weights
  float* ws  = (float*)d_ws;

  float* xp_text  = ws;                                    // 256*64*1024
  float* xp_topic = xp_text + (size_t)TTX * 64 * 1024;     // 16*64*1024
  float* text_o   = xp_topic + (size_t)TTP * 64 * 1024;    // 64*256*512
  float* topic_hv = text_o + (size_t)NB * TTX * HH;        // 64*512
  float* ctx      = topic_hv + (size_t)NB * HH;            // 64*512
  unsigned* hring = (unsigned*)(ctx + (size_t)NB * HH);    // 4*64*512 u32

  sd_init_ring<<<dim3(4 * NB * HH / 256), dim3(256), 0, stream>>>(hring);
  sd_xproj<<<dim3(TTX, 16), dim3(256), 0, stream>>>(text, TTX, emb, tWz, tWo, tbz, tbo, xp_text);
  sd_xproj<<<dim3(TTP, 16), dim3(256), 0, stream>>>(topic, TTP, emb, pWz, pWo, pbz, pbo, xp_topic);
  sd_recur<<<dim3(256), dim3(256), 0, stream>>>(tWz, tWo, pWz, pWo, xp_text, xp_topic,
                                                text_o, hring, topic_hv);
  sd_att<<<dim3(64), dim3(256), 0, stream>>>(text_o, topic_hv, attW, attb, ctx, out + 192);
  sd_fc<<<dim3(64), dim3(256), 0, stream>>>(ctx, topic_hv, fc1W, fc1b, fc2W, fc2b, out);
}

// Round 4
// 972.755 us; speedup vs baseline: 7.3986x; 1.2993x over previous
//
#include <hip/hip_runtime.h>
#include <math.h>

#define NB 64      // batch
#define TTX 256    // text timesteps
#define TTP 16     // topic timesteps
#define EE 300     // embedding dim
#define HH 512     // hidden
#define SENT 0x7FC0DEADu   // NaN-payload sentinel; real h can never be NaN

// ---------------------------------------------------------------------------
// init: poison all 4 h-ring slots (must run each call: graph replays must be
// deterministic and the ring ends a call full of real values)
// ---------------------------------------------------------------------------
__global__ void sd_init_ring(unsigned* __restrict__ hring) {
  hring[blockIdx.x * blockDim.x + threadIdx.x] = SENT;  // grid == 4*NB*HH
}

// ---------------------------------------------------------------------------
// xproj: out[t*64+b][c] = sum_k emb[idx[b][t]][k] * W[k][c'] + bias[c']
// (unchanged)
// ---------------------------------------------------------------------------
__global__ __launch_bounds__(256) void sd_xproj(
    const int* __restrict__ idx, int T,
    const float* __restrict__ emb,
    const float* __restrict__ Wz, const float* __restrict__ Wo,
    const float* __restrict__ bz, const float* __restrict__ bo,
    float* __restrict__ xp)
{
  __shared__ int tok[64];
  __shared__ alignas(16) float As[12][64];
  __shared__ alignas(16) float Bs[12][64];

  const int tid = threadIdx.x;
  const int t   = blockIdx.x;
  const int c0  = blockIdx.y * 64;

  if (tid < 64) tok[tid] = idx[tid * T + t];

  const float* Wsel = (c0 < 512) ? Wz : Wo;
  const float* bsel = (c0 < 512) ? bz : bo;
  const int cc0 = (c0 < 512) ? c0 : (c0 - 512);

  const int tx = tid & 15;
  const int ty = tid >> 4;

  float acc[4][4];
#pragma unroll
  for (int i = 0; i < 4; ++i)
#pragma unroll
    for (int j = 0; j < 4; ++j) acc[i][j] = 0.f;

  __syncthreads();

  const int r   = tid & 63;
  const int k0l = tid >> 6;

  for (int kk = 0; kk < EE; kk += 12) {
    const size_t erow = (size_t)tok[r] * EE + kk + k0l;
    float a0 = emb[erow + 0];
    float a1 = emb[erow + 4];
    float a2 = emb[erow + 8];
    const int j = tid & 63;
    float b0v = Wsel[(size_t)(kk + k0l + 0) * HH + cc0 + j];
    float b1v = Wsel[(size_t)(kk + k0l + 4) * HH + cc0 + j];
    float b2v = Wsel[(size_t)(kk + k0l + 8) * HH + cc0 + j];
    __syncthreads();
    As[k0l + 0][r] = a0;  As[k0l + 4][r] = a1;  As[k0l + 8][r] = a2;
    Bs[k0l + 0][j] = b0v; Bs[k0l + 4][j] = b1v; Bs[k0l + 8][j] = b2v;
    __syncthreads();
#pragma unroll
    for (int k = 0; k < 12; ++k) {
      float4 av = *(const float4*)&As[k][ty * 4];
      float4 bv = *(const float4*)&Bs[k][tx * 4];
      acc[0][0] += av.x * bv.x; acc[0][1] += av.x * bv.y; acc[0][2] += av.x * bv.z; acc[0][3] += av.x * bv.w;
      acc[1][0] += av.y * bv.x; acc[1][1] += av.y * bv.y; acc[1][2] += av.y * bv.z; acc[1][3] += av.y * bv.w;
      acc[2][0] += av.z * bv.x; acc[2][1] += av.z * bv.y; acc[2][2] += av.z * bv.z; acc[2][3] += av.z * bv.w;
      acc[3][0] += av.w * bv.x; acc[3][1] += av.w * bv.y; acc[3][2] += av.w * bv.z; acc[3][3] += av.w * bv.w;
    }
  }

  const float4 bias4 = *(const float4*)&bsel[cc0 + tx * 4];
#pragma unroll
  for (int i = 0; i < 4; ++i) {
    const size_t row = (size_t)t * 64 + (ty * 4 + i);
    float4 o;
    o.x = acc[i][0] + bias4.x;
    o.y = acc[i][1] + bias4.y;
    o.z = acc[i][2] + bias4.z;
    o.w = acc[i][3] + bias4.w;
    *(float4*)&xp[row * 1024 + c0 + tx * 4] = o;
  }
}

// ---------------------------------------------------------------------------
// Persistent recurrence kernel, sentinel-ring, 512-thread edition.
//   256 blocks = 16 batch-groups x 16 dim-slices; 8 waves/block (2/SIMD) so
//   LDS + poll latency is hidden by wave overlap (round-3 ran 1 wave/SIMD).
//   Wave w = k-eighth [w*64, w*64+64); lane = gate(2) x dim(32); wreg[64].
//   Cross-block exchange: 4-deep sentinel ring (see round-3 proof, unchanged):
//     - readers poll slot u&3 words != SENT directly (one MALL hop)
//     - poison own stripe of slot (u-1)&3 only after block-wide poll of slot
//       u&3 succeeded (=> all blocks finished reading slot (u-1)&3)
//     - vmcnt(0) before the real h-store orders poison ahead of the next
//       real value on the same address
// ---------------------------------------------------------------------------
__global__ __launch_bounds__(512) void sd_recur(
    const float* __restrict__ tWz, const float* __restrict__ tWo,
    const float* __restrict__ pWz, const float* __restrict__ pWo,
    const float* __restrict__ xp_text, const float* __restrict__ xp_topic,
    float* __restrict__ text_out, unsigned* __restrict__ hring,
    float* __restrict__ topic_h)
{
  __shared__ alignas(16) float h_s[2][4 * HH];   // staged h rows, double-buffered
  __shared__ alignas(16) float red[2][2048];     // [8 kq][2 gt][4 row][32 d], dbuf

  const int tid = threadIdx.x;
  const int bid = blockIdx.x;
  const int x = bid & 7;           // XCD (heuristic placement)
  const int q = bid >> 3;
  const int g = x + 8 * (q >> 4);  // batch group 0..15
  const int slice = q & 15;        // dim slice 0..15
  const int b0 = g * 4;
  const int c_base = slice * 32;

  const int wv = tid >> 6;         // wave id = k-eighth (0..7)
  const int lane = tid & 63;
  const int gt = lane >> 5;        // 0 = z gate, 1 = o gate
  const int d = lane & 31;
  const int c = c_base + d;

  const int bi_w = tid >> 5;       // writer mapping (tid<128): batch row 0..3
  const int dw = tid & 31;

  // writer thread's private ring word offset (within a slot)
  const size_t wslot_off = (size_t)(b0 + bi_w) * HH + c_base + dw;

  int u = 0;  // global step counter across both phases

  for (int ph = 0; ph < 2; ++ph) {
    const float* Wg = gt ? (ph ? pWo : tWo) : (ph ? pWz : tWz);
    const float* xp = ph ? xp_topic : xp_text;
    const int T = ph ? TTP : TTX;

    // this lane's W h-part column slice (k-eighth) into registers
    float wreg[64];
#pragma unroll
    for (int kk = 0; kk < 64; ++kk)
      wreg[kk] = Wg[(size_t)(EE + wv * 64 + kk) * HH + c];

    for (int t = 0; t < T; ++t, ++u) {
      const int cur = u & 1;
      const bool do_poll = (u > 0);
      const bool use_h   = (t > 0);

      // xp prefetch early (latency hidden under poll)
      float xpz = 0.f, xpo = 0.f;
      if (tid < 128) {
        const float* xpr = xp + ((size_t)t * 64 + (b0 + bi_w)) * 1024 + c_base + dw;
        xpz = xpr[0];
        xpo = xpr[512];
      }

      if (do_poll) {
        // poll-stage 2048 words of slot u&3 (4 words/thread) into LDS
        const unsigned* src = hring + (size_t)(u & 3) * NB * HH + (size_t)b0 * HH;
        unsigned v0, v1, v2, v3;
        for (;;) {
          v0 = __hip_atomic_load(&src[tid + 0 * 512], __ATOMIC_RELAXED, __HIP_MEMORY_SCOPE_AGENT);
          v1 = __hip_atomic_load(&src[tid + 1 * 512], __ATOMIC_RELAXED, __HIP_MEMORY_SCOPE_AGENT);
          v2 = __hip_atomic_load(&src[tid + 2 * 512], __ATOMIC_RELAXED, __HIP_MEMORY_SCOPE_AGENT);
          v3 = __hip_atomic_load(&src[tid + 3 * 512], __ATOMIC_RELAXED, __HIP_MEMORY_SCOPE_AGENT);
          if (v0 != SENT && v1 != SENT && v2 != SENT && v3 != SENT) break;
          __builtin_amdgcn_s_sleep(1);
        }
        h_s[cur][tid + 0 * 512] = __uint_as_float(v0);
        h_s[cur][tid + 1 * 512] = __uint_as_float(v1);
        h_s[cur][tid + 2 * 512] = __uint_as_float(v2);
        h_s[cur][tid + 3 * 512] = __uint_as_float(v3);
      }

      __syncthreads();  // whole block's poll complete + stage visible

      // Safe to recycle slot (u-1)&3 now (see header proof).
      if (do_poll && tid < 128)
        __hip_atomic_store(&hring[(size_t)((u - 1) & 3) * NB * HH + wslot_off],
                           SENT, __ATOMIC_RELAXED, __HIP_MEMORY_SCOPE_AGENT);

      if (use_h) {
        float acc0 = 0.f, acc1 = 0.f, acc2 = 0.f, acc3 = 0.f;
        const float* hq = &h_s[cur][wv * 64];
#pragma unroll
        for (int k4 = 0; k4 < 16; ++k4) {
          const float w0 = wreg[4 * k4 + 0], w1 = wreg[4 * k4 + 1];
          const float w2 = wreg[4 * k4 + 2], w3 = wreg[4 * k4 + 3];
          float4 h0v = *(const float4*)(hq + 0 * HH + 4 * k4);
          float4 h1v = *(const float4*)(hq + 1 * HH + 4 * k4);
          float4 h2v = *(const float4*)(hq + 2 * HH + 4 * k4);
          float4 h3v = *(const float4*)(hq + 3 * HH + 4 * k4);
          acc0 += h0v.x * w0 + h0v.y * w1 + h0v.z * w2 + h0v.w * w3;
          acc1 += h1v.x * w0 + h1v.y * w1 + h1v.z * w2 + h1v.w * w3;
          acc2 += h2v.x * w0 + h2v.y * w1 + h2v.z * w2 + h2v.w * w3;
          acc3 += h3v.x * w0 + h3v.y * w1 + h3v.z * w2 + h3v.w * w3;
        }
        float* rp = &red[cur][((wv * 2 + gt) * 4) * 32 + d];
        rp[0 * 32] = acc0; rp[1 * 32] = acc1; rp[2 * 32] = acc2; rp[3 * 32] = acc3;
      }

      __syncthreads();  // partials visible

      if (tid < 128) {
        float zp = 0.f, op = 0.f;
        if (use_h) {
#pragma unroll
          for (int k2 = 0; k2 < 8; ++k2) {
            zp += red[cur][((k2 * 2 + 0) * 4 + bi_w) * 32 + dw];
            op += red[cur][((k2 * 2 + 1) * 4 + bi_w) * 32 + dw];
          }
        }
        const float a = zp + xpz;
        const float z = 1.f / (1.f + __expf(-a));
        const float bv = op + xpo;
        const float ab = fabsf(bv);
        const float e2 = __expf(-2.f * ab);
        const float htl = __builtin_copysignf((1.f - e2) / (1.f + e2), bv);
        const float hprev = use_h ? h_s[cur][bi_w * HH + c_base + dw] : 0.f;
        const float hn = (1.f - z) * hprev + z * htl;

        // this step's poison must be at the coherence point before the real
        // store below becomes visible (same-address stale-real proof)
        asm volatile("s_waitcnt vmcnt(0)" ::: "memory");
        __hip_atomic_store(&hring[(size_t)((u + 1) & 3) * NB * HH + wslot_off],
                           __float_as_uint(hn), __ATOMIC_RELAXED, __HIP_MEMORY_SCOPE_AGENT);
        if (ph == 0)
          text_out[((size_t)(b0 + bi_w) * TTX + t) * HH + c_base + dw] = hn;
        else if (t == T - 1)
          topic_h[(size_t)(b0 + bi_w) * HH + c_base + dw] = hn;
      }
      // no trailing barrier: h_s/red double-buffering tolerates one-phase skew
    }
  }
}

// ---------------------------------------------------------------------------
// attention: scores -> softmax weights (output) -> context  (unchanged)
// ---------------------------------------------------------------------------
__global__ __launch_bounds__(256) void sd_att(
    const float* __restrict__ text_out, const float* __restrict__ topic_h,
    const float* __restrict__ att_W, const float* __restrict__ att_b,
    float* __restrict__ context, float* __restrict__ weights_out)
{
  __shared__ alignas(16) float aw[1024];
  __shared__ float sred[256];
  __shared__ float wsh[256];
  const int b = blockIdx.x, tid = threadIdx.x;

  for (int i = tid; i < 1024; i += 256) aw[i] = att_W[i];
  __syncthreads();

  float part = 0.f;
  for (int i = tid; i < 512; i += 256) part += topic_h[(size_t)b * HH + i] * aw[512 + i];
  sred[tid] = part;
  __syncthreads();
  for (int s = 128; s > 0; s >>= 1) { if (tid < s) sred[tid] += sred[tid + s]; __syncthreads(); }
  const float cb = sred[0] + att_b[0];
  __syncthreads();

  const float* row = text_out + ((size_t)b * TTX + tid) * HH;
  float sc = cb;
  for (int d4 = 0; d4 < 128; ++d4) {
    float4 v = ((const float4*)row)[d4];
    float4 w4 = ((const float4*)aw)[d4];
    sc += v.x * w4.x + v.y * w4.y + v.z * w4.z + v.w * w4.w;
  }
  sred[tid] = sc; __syncthreads();
  for (int s = 128; s > 0; s >>= 1) { if (tid < s) sred[tid] = fmaxf(sred[tid], sred[tid + s]); __syncthreads(); }
  const float m = sred[0];
  __syncthreads();
  const float e = expf(sc - m);
  sred[tid] = e; __syncthreads();
  for (int s = 128; s > 0; s >>= 1) { if (tid < s) sred[tid] += sred[tid + s]; __syncthreads(); }
  const float wv = e / sred[0];
  wsh[tid] = wv;
  weights_out[(size_t)b * TTX + tid] = wv;
  __syncthreads();

  for (int rep = 0; rep < 2; ++rep) {
    const int dcol = rep * 256 + tid;
    float accc = 0.f;
    const float* base = text_out + (size_t)b * TTX * HH + dcol;
    for (int t2 = 0; t2 < TTX; ++t2) accc += wsh[t2] * base[(size_t)t2 * HH];
    context[(size_t)b * HH + dcol] = accc;
  }
}

// ---------------------------------------------------------------------------
// FC head: feat=[context, topic_h] -> relu(fc1) -> fc2 logits  (unchanged)
// ---------------------------------------------------------------------------
__global__ __launch_bounds__(256) void sd_fc(
    const float* __restrict__ context, const float* __restrict__ topic_h,
    const float* __restrict__ fc1_W, const float* __restrict__ fc1_b,
    const float* __restrict__ fc2_W, const float* __restrict__ fc2_b,
    float* __restrict__ logits)
{
  __shared__ alignas(16) float feat[1024];
  __shared__ float hid[512];
  const int b = blockIdx.x, tid = threadIdx.x;

  for (int i = tid; i < 512; i += 256) {
    feat[i]       = context[(size_t)b * HH + i];
    feat[512 + i] = topic_h[(size_t)b * HH + i];
  }
  __syncthreads();

  for (int rep = 0; rep < 2; ++rep) {
    const int dcol = rep * 256 + tid;
    float a = fc1_b[dcol];
#pragma unroll 4
    for (int j = 0; j < 1024; ++j) a += feat[j] * fc1_W[(size_t)j * HH + dcol];
    hid[dcol] = fmaxf(a, 0.f);
  }
  __syncthreads();

  float p0 = 0.f, p1 = 0.f, p2 = 0.f;
  for (int dv = tid; dv < 512; dv += 256) {
    const float hv = hid[dv];
    p0 += hv * fc2_W[dv * 3 + 0];
    p1 += hv * fc2_W[dv * 3 + 1];
    p2 += hv * fc2_W[dv * 3 + 2];
  }
  feat[tid] = p0; feat[256 + tid] = p1; feat[512 + tid] = p2;
  __syncthreads();
  for (int s = 128; s > 0; s >>= 1) {
    if (tid < s) {
      feat[tid] += feat[tid + s];
      feat[256 + tid] += feat[256 + tid + s];
      feat[512 + tid] += feat[512 + tid + s];
    }
    __syncthreads();
  }
  if (tid < 3) logits[b * 3 + tid] = feat[tid * 256] + fc2_b[tid];
}

// ---------------------------------------------------------------------------
extern "C" void kernel_launch(void* const* d_in, const int* in_sizes, int n_in,
                              void* d_out, int out_size, void* d_ws, size_t ws_size,
                              hipStream_t stream) {
  const int*   text  = (const int*)d_in[0];
  const int*   topic = (const int*)d_in[1];
  const float* emb   = (const float*)d_in[2];
  const float* tWz   = (const float*)d_in[3];
  const float* tbz   = (const float*)d_in[4];
  const float* tWo   = (const float*)d_in[5];
  const float* tbo   = (const float*)d_in[6];
  const float* pWz   = (const float*)d_in[7];
  const float* pbz   = (const float*)d_in[8];
  const float* pWo   = (const float*)d_in[9];
  const float* pbo   = (const float*)d_in[10];
  const float* attW  = (const float*)d_in[11];
  const float* attb  = (const float*)d_in[12];
  const float* fc1W  = (const float*)d_in[13];
  const float* fc1b  = (const float*)d_in[14];
  const float* fc2W  = (const float*)d_in[15];
  const float* fc2b  = (const float*)d_in[16];

  float* out = (float*)d_out;            // [0,192): logits, [192,+16384): weights
  float* ws  = (float*)d_ws;

  float* xp_text  = ws;                                    // 256*64*1024
  float* xp_topic = xp_text + (size_t)TTX * 64 * 1024;     // 16*64*1024
  float* text_o   = xp_topic + (size_t)TTP * 64 * 1024;    // 64*256*512
  float* topic_hv = text_o + (size_t)NB * TTX * HH;        // 64*512
  float* ctx      = topic_hv + (size_t)NB * HH;            // 64*512
  unsigned* hring = (unsigned*)(ctx + (size_t)NB * HH);    // 4*64*512 u32

  sd_init_ring<<<dim3(4 * NB * HH / 256), dim3(256), 0, stream>>>(hring);
  sd_xproj<<<dim3(TTX, 16), dim3(256), 0, stream>>>(text, TTX, emb, tWz, tWo, tbz, tbo, xp_text);
  sd_xproj<<<dim3(TTP, 16), dim3(256), 0, stream>>>(topic, TTP, emb, pWz, pWo, pbz, pbo, xp_topic);
  sd_recur<<<dim3(256), dim3(512), 0, stream>>>(tWz, tWo, pWz, pWo, xp_text, xp_topic,
                                                text_o, hring, topic_hv);
  sd_att<<<dim3(64), dim3(256), 0, stream>>>(text_o, topic_hv, attW, attb, ctx, out + 192);
  sd_fc<<<dim3(64), dim3(256), 0, stream>>>(ctx, topic_hv, fc1W, fc1b, fc2W, fc2b, out);
}